// Round 8
// baseline (364.829 us; speedup 1.0000x reference)
//
#include <hip/hip_runtime.h>
#include <hip/hip_bf16.h>
#include <hip/hip_fp16.h>

#define DIM 512
#define HID 2048
#define NE 8
#define NTOK 4096

typedef _Float16 v8h __attribute__((ext_vector_type(8)));
typedef _Float16 v4h __attribute__((ext_vector_type(4)));
typedef float v16f __attribute__((ext_vector_type(16)));

__device__ __forceinline__ void load16(const void* g, void* l) {
  __builtin_amdgcn_global_load_lds(
      (const __attribute__((address_space(1))) unsigned int*)g,
      (__attribute__((address_space(3))) unsigned int*)l, 16, 0, 0);
}

// tanh-form GELU: v * sigmoid(1.5957691*v + 0.07135482*v^3), |err| vs erf-GELU ~5e-4
__device__ __forceinline__ float gelu_fast(float v) {
  float v2 = v * v;
  float u = v * __builtin_fmaf(0.07135481627f, v2, 1.5957691216f);
  float t = __expf(-u);
  return v * __builtin_amdgcn_rcpf(1.0f + t);
}

// Routing: 1024 blocks x 4 tokens (x->f16, leaf probs, out bias-init).
__global__ __launch_bounds__(256) void route_kernel(const float* __restrict__ x,
                                                    const float* __restrict__ rw,
                                                    const float* __restrict__ rb,
                                                    const float* __restrict__ b2,
                                                    float* __restrict__ leaf,
                                                    _Float16* __restrict__ xh,
                                                    float* __restrict__ out) {
  const int lane = threadIdx.x & 63;
  const int wave = threadIdx.x >> 6;
  const int n = (blockIdx.x << 2) + wave;
  const float4* xv = (const float4*)(x + (size_t)n * DIM);
  const float4 x0 = xv[lane * 2], x1 = xv[lane * 2 + 1];
  v8h o;
  o[0] = (_Float16)x0.x; o[1] = (_Float16)x0.y; o[2] = (_Float16)x0.z; o[3] = (_Float16)x0.w;
  o[4] = (_Float16)x1.x; o[5] = (_Float16)x1.y; o[6] = (_Float16)x1.z; o[7] = (_Float16)x1.w;
  *(v8h*)(xh + (size_t)n * DIM + lane * 8) = o;
  float logits[7];
#pragma unroll
  for (int rr = 0; rr < 7; ++rr) {
    const float4* wv = (const float4*)(rw + rr * DIM);
    const float4 w0 = wv[lane * 2], w1v = wv[lane * 2 + 1];
    float s = x0.x * w0.x + x0.y * w0.y + x0.z * w0.z + x0.w * w0.w +
              x1.x * w1v.x + x1.y * w1v.y + x1.z * w1v.z + x1.w * w1v.w;
#pragma unroll
    for (int o2 = 32; o2; o2 >>= 1) s += __shfl_xor(s, o2, 64);
    logits[rr] = s + rb[rr];
  }
  const int eidx = lane & 7;
  const float p0 = 1.f / (1.f + __expf(-logits[0]));
  float f = ((eidx >> 2) & 1) ? p0 : 1.f - p0;
  const float p1 = 1.f / (1.f + __expf(-logits[1 + (eidx >> 2)]));
  f *= ((eidx >> 1) & 1) ? p1 : 1.f - p1;
  const float p2 = 1.f / (1.f + __expf(-logits[3 + (eidx >> 1)]));
  f *= (eidx & 1) ? p2 : 1.f - p2;
  if (lane < NE) leaf[(size_t)n * NE + lane] = f;
  float le[NE];
#pragma unroll
  for (int e = 0; e < NE; ++e) le[e] = __shfl(f, e, 64);
  float4 a0 = {0.f, 0.f, 0.f, 0.f}, a1 = {0.f, 0.f, 0.f, 0.f};
#pragma unroll
  for (int e = 0; e < NE; ++e) {
    const float4* bv = (const float4*)(b2 + (size_t)e * DIM + lane * 8);
    const float4 u0 = bv[0], u1 = bv[1];
    a0.x += le[e] * u0.x; a0.y += le[e] * u0.y; a0.z += le[e] * u0.z; a0.w += le[e] * u0.w;
    a1.x += le[e] * u1.x; a1.y += le[e] * u1.y; a1.z += le[e] * u1.z; a1.w += le[e] * u1.w;
  }
  float4* op = (float4*)(out + (size_t)n * DIM + lane * 8);
  op[0] = a0; op[1] = a1;
}

// Weight transpose fp32 [E][Rk][C] -> f16 [E][C][Rk]; strip = 32 rows x 256 cols.
// Wide ops both sides: phase 1 = coalesced float4 reads + 4x4 in-register
// micro-transpose + ds_write_b64; phase 2 = 8x ds_read_b64 + 4x 16B global store.
// (Old version did 64 scalar ds_read_u16 per thread in phase 2.)
__global__ __launch_bounds__(256) void trans_kernel(const float* __restrict__ w1,
                                                    const float* __restrict__ w2,
                                                    _Float16* __restrict__ w1t,
                                                    _Float16* __restrict__ w2t) {
  __shared__ _Float16 tlT[256][36];   // [col][row+pad]; row stride 72B (8B-aligned, ~4-way)
  int b = blockIdx.x;
  const float* in;
  _Float16* outp;
  int C, Rk, kt, ct, e;
  if (b < 1024) {       // w1: [E][512][2048] -> w1t [E][2048][512]
    in = w1; outp = w1t; C = HID; Rk = DIM;
    e = b >> 7; const int rem = b & 127; kt = rem & 15; ct = rem >> 4;
  } else {              // w2: [E][2048][512] -> w2t [E][512][2048]
    b -= 1024;
    in = w2; outp = w2t; C = DIM; Rk = HID;
    e = b >> 7; const int rem = b & 127; kt = rem & 63; ct = rem >> 6;
  }
  const int k0 = kt << 5, c0 = ct << 8;
  const size_t ebase = (size_t)e * Rk * C;
  const int tid = threadIdx.x;
#pragma unroll
  for (int it = 0; it < 2; ++it) {
    const int mb = (it << 8) + tid;
    const int rg = mb >> 6, cq = mb & 63;     // 8 row-groups x 64 col-quads
    const float* sp = in + ebase + (size_t)(k0 + (rg << 2)) * C + c0 + (cq << 2);
    const float4 r0 = *(const float4*)(sp);
    const float4 r1 = *(const float4*)(sp + C);
    const float4 r2 = *(const float4*)(sp + 2 * C);
    const float4 r3 = *(const float4*)(sp + 3 * C);
    const int cc = cq << 2, rr = rg << 2;
    v4h t0 = {(_Float16)r0.x, (_Float16)r1.x, (_Float16)r2.x, (_Float16)r3.x};
    v4h t1 = {(_Float16)r0.y, (_Float16)r1.y, (_Float16)r2.y, (_Float16)r3.y};
    v4h t2 = {(_Float16)r0.z, (_Float16)r1.z, (_Float16)r2.z, (_Float16)r3.z};
    v4h t3 = {(_Float16)r0.w, (_Float16)r1.w, (_Float16)r2.w, (_Float16)r3.w};
    *(v4h*)&tlT[cc + 0][rr] = t0;
    *(v4h*)&tlT[cc + 1][rr] = t1;
    *(v4h*)&tlT[cc + 2][rr] = t2;
    *(v4h*)&tlT[cc + 3][rr] = t3;
  }
  __syncthreads();
  // phase 2: one output col per thread: 32 f16 row gather (wide) + 64B write
  v8h ov[4];
#pragma unroll
  for (int g = 0; g < 4; ++g) {
    const v4h lo = *(const v4h*)&tlT[tid][g * 8];
    const v4h hi = *(const v4h*)&tlT[tid][g * 8 + 4];
    ov[g][0] = lo[0]; ov[g][1] = lo[1]; ov[g][2] = lo[2]; ov[g][3] = lo[3];
    ov[g][4] = hi[0]; ov[g][5] = hi[1]; ov[g][6] = hi[2]; ov[g][7] = hi[3];
  }
  _Float16* dp = outp + ebase + (size_t)(c0 + tid) * Rk + k0;
#pragma unroll
  for (int g = 0; g < 4; ++g) *(v8h*)(dp + g * 8) = ov[g];
}

// ---- GEMMs: 128x128 tile, 4 waves (2x2 of 64x64), BK=64, DOUBLE-BUFFERED LDS
// (2x32 KiB = 64 KiB -> 2 blocks/CU), T3-minimum 2-phase schedule:
//   STAGE(next tile) issued FIRST; frag ds_reads + MFMA cluster on current
//   buffer; then vmcnt(0) + ONE raw s_barrier per K-tile (stage latency hides
//   under the ~350cy compute phase; no pre-compute drain, no second barrier).
// Safety: reads of buf[cur] were published by last tile's vmcnt(0)+barrier;
// stage writes target buf[cur^1], whose readers all passed that same barrier.

#define WAIT0() asm volatile("s_waitcnt vmcnt(0)" ::: "memory")
#define BARF()                                                                \
  {                                                                           \
    __builtin_amdgcn_s_barrier();                                             \
    asm volatile("" ::: "memory");                                            \
  }

#define GSTAGE(BOF, KO)                                                       \
  {                                                                           \
    _Pragma("unroll") for (int i = 0; i < 4; ++i)                             \
        load16(pa[i] + (KO), la[i] + (BOF));                                  \
    _Pragma("unroll") for (int i = 0; i < 4; ++i)                             \
        load16(pb[i] + (KO), lb[i] + (BOF));                                  \
  }

#define GCOMPUTE(BOF)                                                         \
  {                                                                           \
    v8h a[2][4], b[2][4];                                                     \
    _Pragma("unroll") for (int ks = 0; ks < 4; ++ks) {                        \
      const int so = (BOF) + ((((ks << 1) + h2) ^ cx) << 3);                  \
      a[0][ks] = *(const v8h*)(fA[0] + so);                                   \
      a[1][ks] = *(const v8h*)(fA[1] + so);                                   \
      b[0][ks] = *(const v8h*)(fB[0] + so);                                   \
      b[1][ks] = *(const v8h*)(fB[1] + so);                                   \
    }                                                                         \
    __builtin_amdgcn_s_setprio(1);                                            \
    _Pragma("unroll") for (int ks = 0; ks < 4; ++ks)                          \
      _Pragma("unroll") for (int i = 0; i < 2; ++i)                           \
        _Pragma("unroll") for (int j = 0; j < 2; ++j)                         \
          acc[i][j] = __builtin_amdgcn_mfma_f32_32x32x16_f16(a[i][ks], b[j][ks], acc[i][j], 0, 0, 0); \
    __builtin_amdgcn_s_setprio(0);                                            \
  }

#define GITER(BUFC, BUFS, KO)                                                 \
  {                                                                           \
    GSTAGE(BUFS, KO);                                                         \
    GCOMPUTE(BUFC);                                                           \
    WAIT0();                                                                  \
    BARF();                                                                   \
  }

// H'[e][n][h] = leaf[n,e] * gelu(X @ W1[e]^T + b1[e]); K=512 -> 8 tiles.
__global__ __launch_bounds__(256, 2) void gemm1_kernel(const _Float16* __restrict__ xh,
                                                       const _Float16* __restrict__ w1t,
                                                       const float* __restrict__ b1,
                                                       const float* __restrict__ leaf,
                                                       _Float16* __restrict__ H) {
  const int bx = blockIdx.x;
  const int e = bx & 7;                  // expert == XCD: W1t[e] L2-resident
  const int t = bx >> 3;
  const int mt = t & 31;                 // 32 m-tiles of 128
  const int nt = t >> 5;                 // 16 n-tiles of 128
  const int m0 = mt << 7, n0 = nt << 7;

  __shared__ alignas(16) _Float16 As[2 * 128 * 64];   // 32 KiB (dbuf)
  __shared__ alignas(16) _Float16 Bs[2 * 128 * 64];   // 32 KiB

  const int tid = threadIdx.x;
  const int lane = tid & 63;
  const int wave = tid >> 6;
  const int wm = wave >> 1, wn = wave & 1;
  const int c = lane & 31, h2 = lane >> 5;
  const int cx = c & 7;

  const int strow = tid >> 3;            // 0..31
  const int c8 = (tid & 7) ^ (strow & 7);
  const _Float16* pa[4];
  const _Float16* pb[4];
  _Float16* la[4];
  _Float16* lb[4];
#pragma unroll
  for (int i = 0; i < 4; ++i) {
    pa[i] = xh + (size_t)(m0 + strow + 32 * i) * DIM + (c8 << 3);
    la[i] = As + tid * 8 + i * 2048;
    pb[i] = w1t + ((size_t)e * HID + n0 + strow + 32 * i) * DIM + (c8 << 3);
    lb[i] = Bs + tid * 8 + i * 2048;
  }
  const _Float16* fA[2];
  const _Float16* fB[2];
#pragma unroll
  for (int i = 0; i < 2; ++i) fA[i] = As + ((wm << 6) + (i << 5) + c) * 64;
#pragma unroll
  for (int j = 0; j < 2; ++j) fB[j] = Bs + ((wn << 6) + (j << 5) + c) * 64;

  v16f acc[2][2];
#pragma unroll
  for (int i = 0; i < 2; ++i)
#pragma unroll
    for (int j = 0; j < 2; ++j)
      acc[i][j] = v16f{0.f,0.f,0.f,0.f,0.f,0.f,0.f,0.f,0.f,0.f,0.f,0.f,0.f,0.f,0.f,0.f};

  // 2-phase dbuf pipeline, K=512 = 8 tiles, fully unrolled
  GSTAGE(0, 0);
  WAIT0(); BARF();
  GITER(0, 8192, 64);     // compute t0(buf0), stage t1->buf1
  GITER(8192, 0, 128);
  GITER(0, 8192, 192);
  GITER(8192, 0, 256);
  GITER(0, 8192, 320);
  GITER(8192, 0, 384);
  GITER(0, 8192, 448);    // compute t6, stage t7->buf1
  GCOMPUTE(8192);         // t7

  // epilogue: C/D map col=lane&31, row=(reg&3)+8*(reg>>2)+4*(lane>>5)
  const float* b1e = b1 + (size_t)e * HID;
  _Float16* He = H + (size_t)e * NTOK * HID;
  const int colb = n0 + (wn << 6) + c;
  const float bias0 = b1e[colb];
  const float bias1 = b1e[colb + 32];
#pragma unroll
  for (int i = 0; i < 2; ++i) {
    const int rb0 = m0 + (wm << 6) + (i << 5) + (h2 << 2);
#pragma unroll
    for (int rg = 0; rg < 4; ++rg) {
#pragma unroll
      for (int rr = 0; rr < 4; ++rr) {
        const int row = rb0 + (rg << 3) + rr;
        const int reg = (rg << 2) + rr;
        const float p = leaf[(size_t)row * NE + e];
        _Float16* hp = He + (size_t)row * HID + colb;
        hp[0]  = (_Float16)(p * gelu_fast(acc[i][0][reg] + bias0));
        hp[32] = (_Float16)(p * gelu_fast(acc[i][1][reg] + bias1));
      }
    }
  }
}

// out += H'[e] @ W2[e]^T, split-K by expert; 128x128 tile, K=2048 -> 32 tiles.
__global__ __launch_bounds__(256, 2) void gemm2_kernel(const _Float16* __restrict__ H,
                                                       const _Float16* __restrict__ w2t,
                                                       float* __restrict__ out) {
  const int bx = blockIdx.x;
  const int e = bx & 7;                  // expert == XCD
  const int dt = (bx >> 3) & 3;          // dt fastest: d-blocks of an m-slice co-resident
  const int mt = bx >> 5;                // 32 m-tiles of 128
  const int m0 = mt << 7, d0 = dt << 7;

  __shared__ alignas(16) _Float16 As[2 * 128 * 64];
  __shared__ alignas(16) _Float16 Bs[2 * 128 * 64];

  const int tid = threadIdx.x;
  const int lane = tid & 63;
  const int wave = tid >> 6;
  const int wm = wave >> 1, wn = wave & 1;
  const int c = lane & 31, h2 = lane >> 5;
  const int cx = c & 7;

  const int strow = tid >> 3;
  const int c8 = (tid & 7) ^ (strow & 7);
  const _Float16* pa[4];
  const _Float16* pb[4];
  _Float16* la[4];
  _Float16* lb[4];
#pragma unroll
  for (int i = 0; i < 4; ++i) {
    pa[i] = H + ((size_t)e * NTOK + m0 + strow + 32 * i) * HID + (c8 << 3);
    la[i] = As + tid * 8 + i * 2048;
    pb[i] = w2t + ((size_t)e * DIM + d0 + strow + 32 * i) * HID + (c8 << 3);
    lb[i] = Bs + tid * 8 + i * 2048;
  }
  const _Float16* fA[2];
  const _Float16* fB[2];
#pragma unroll
  for (int i = 0; i < 2; ++i) fA[i] = As + ((wm << 6) + (i << 5) + c) * 64;
#pragma unroll
  for (int j = 0; j < 2; ++j) fB[j] = Bs + ((wn << 6) + (j << 5) + c) * 64;

  v16f acc[2][2];
#pragma unroll
  for (int i = 0; i < 2; ++i)
#pragma unroll
    for (int j = 0; j < 2; ++j)
      acc[i][j] = v16f{0.f,0.f,0.f,0.f,0.f,0.f,0.f,0.f,0.f,0.f,0.f,0.f,0.f,0.f,0.f,0.f};

  // 2-phase dbuf pipeline, K=2048 = 32 tiles: 15 pairs + final pair
  GSTAGE(0, 0);
  WAIT0(); BARF();
  for (int ko = 0; ko < 15; ++ko) {
    GITER(0, 8192, 64);    // compute even tile (buf0), stage odd -> buf1
    GITER(8192, 0, 128);   // compute odd tile (buf1), stage next even -> buf0
#pragma unroll
    for (int i = 0; i < 4; ++i) { pa[i] += 128; pb[i] += 128; }
  }
  GITER(0, 8192, 64);      // compute t30, stage t31 -> buf1
  GCOMPUTE(8192);          // t31

#pragma unroll
  for (int i = 0; i < 2; ++i) {
    const int rb0 = m0 + (wm << 6) + (i << 5) + (h2 << 2);
#pragma unroll
    for (int rg = 0; rg < 4; ++rg) {
#pragma unroll
      for (int rr = 0; rr < 4; ++rr) {
        const int row = rb0 + (rg << 3) + rr;
        const int reg = (rg << 2) + rr;
        float* op = out + (size_t)row * DIM + d0 + (wn << 6) + c;
        atomicAdd(op, acc[i][0][reg]);
        atomicAdd(op + 32, acc[i][1][reg]);
      }
    }
  }
}

extern "C" void kernel_launch(void* const* d_in, const int* in_sizes, int n_in,
                              void* d_out, int out_size, void* d_ws, size_t ws_size,
                              hipStream_t stream) {
  const float* x  = (const float*)d_in[0];
  const float* rw = (const float*)d_in[1];
  const float* rb = (const float*)d_in[2];
  const float* w1 = (const float*)d_in[3];
  const float* b1 = (const float*)d_in[4];
  const float* w2 = (const float*)d_in[5];
  const float* b2 = (const float*)d_in[6];
  float* out = (float*)d_out;

  char* ws = (char*)d_ws;
  const size_t xh_bytes   = (size_t)NTOK * DIM * 2;       // 4 MiB
  const size_t w1t_bytes  = (size_t)NE * HID * DIM * 2;   // 16 MiB
  const size_t w2t_bytes  = (size_t)NE * DIM * HID * 2;   // 16 MiB
  const size_t leaf_bytes = (size_t)NTOK * NE * 4;        // 128 KiB
  const size_t H_bytes    = (size_t)NE * NTOK * HID * 2;  // 128 MiB
  _Float16* xh   = (_Float16*)(ws);
  _Float16* w1t  = (_Float16*)(ws + xh_bytes);
  _Float16* w2t  = (_Float16*)(ws + xh_bytes + w1t_bytes);
  float*    leaf = (float*)(ws + xh_bytes + w1t_bytes + w2t_bytes);
  _Float16* Hbuf = (_Float16*)(ws + xh_bytes + w1t_bytes + w2t_bytes + leaf_bytes);
  if (ws_size < xh_bytes + w1t_bytes + w2t_bytes + leaf_bytes + H_bytes) return;

  route_kernel<<<1024, 256, 0, stream>>>(x, rw, rb, b2, leaf, xh, out);
  trans_kernel<<<2048, 256, 0, stream>>>(w1, w2, w1t, w2t);
  gemm1_kernel<<<4096, 256, 0, stream>>>(xh, w1t, b1, leaf, Hbuf);
  gemm2_kernel<<<1024, 256, 0, stream>>>(Hbuf, w2t, out);
}